// Round 15
// baseline (326.806 us; speedup 1.0000x reference)
//
#include <hip/hip_runtime.h>

// GCN: 3x GCNConv(64->64) + mean-pool(32 graphs) + linear(64->2), fp32.
// Preproc: histogram WITH RANK CAPTURE -> scan -> CSR fill (no atomics).
// GEMM: 16 threads/row x float4 cols, dual accumulators. Conv: 8 lanes/node
// (2x float4 per lane), 8 node streams/wave, hand-interleaved 2-edge loop
// with 4 independent accumulators -> 4 gathers in flight per lane.

#define FEAT 64
#define NGRAPH 32
#define SCAN_BLK 512
#define POOL_SPAN 64

__device__ __forceinline__ float4 fma4(float s, float4 v, float4 a) {
    a.x = fmaf(s, v.x, a.x); a.y = fmaf(s, v.y, a.y);
    a.z = fmaf(s, v.z, a.z); a.w = fmaf(s, v.w, a.w);
    return a;
}

// ---------------- preprocessing ----------------

// histogram + rank: rank[i] = old count = position of edge i within its dst row
__global__ void k_cnt(const int* __restrict__ dst, int* __restrict__ cnt,
                      int* __restrict__ rank, int e) {
    int i = blockIdx.x * blockDim.x + threadIdx.x;
    int stride = gridDim.x * blockDim.x;
    for (; i < e; i += stride) rank[i] = atomicAdd(&cnt[dst[i]], 1);
}

// per-block inclusive scan of cnt -> local-exclusive row_ptr + block sums
__global__ void k_scan_block(const int* __restrict__ cnt, int n,
                             int* __restrict__ row_ptr, int* __restrict__ part) {
    __shared__ int s[SCAN_BLK];
    int tid = threadIdx.x;
    int i = blockIdx.x * SCAN_BLK + tid;
    int v = (i < n) ? cnt[i] : 0;
    s[tid] = v;
    __syncthreads();
    for (int o = 1; o < SCAN_BLK; o <<= 1) {
        int t = (tid >= o) ? s[tid - o] : 0;
        __syncthreads();
        s[tid] += t;
        __syncthreads();
    }
    if (i < n) row_ptr[i] = s[tid] - v;          // local exclusive
    if (tid == SCAN_BLK - 1) part[blockIdx.x] = s[tid];
}

__global__ void k_scan_top(int* __restrict__ part, int nb) {
    __shared__ int s[SCAN_BLK];
    int tid = threadIdx.x;
    int v = (tid < nb) ? part[tid] : 0;
    s[tid] = v;
    __syncthreads();
    for (int o = 1; o < SCAN_BLK; o <<= 1) {
        int t = (tid >= o) ? s[tid - o] : 0;
        __syncthreads();
        s[tid] += t;
        __syncthreads();
    }
    if (tid < nb) part[tid] = s[tid] - v;        // exclusive block offsets
}

__global__ void k_scan_add(int* __restrict__ row_ptr, const int* __restrict__ part,
                           int n, int e) {
    int i = blockIdx.x * blockDim.x + threadIdx.x;
    if (i < n) row_ptr[i] += part[i >> 9];       // 512 = 2^9
    if (i == 0) row_ptr[n] = e;
}

// CSR entry int2{src, ew-bits}; pos from precomputed rank -> NO atomics
__global__ void k_fill(const int* __restrict__ src, const int* __restrict__ dst,
                       const float* __restrict__ ew, const int* __restrict__ rank,
                       const int* __restrict__ row_ptr, int2* __restrict__ csr, int e) {
    int i = blockIdx.x * blockDim.x + threadIdx.x;
    int stride = gridDim.x * blockDim.x;
    for (; i < e; i += stride) {
        int pos = row_ptr[dst[i]] + rank[i];
        csr[pos] = make_int2(src[i], __float_as_int(ew[i]));
    }
}

// deg = 1 + sum(ew over own CSR row); dis = rsqrt(deg). No atomics.
__global__ void k_degdis(const int* __restrict__ row_ptr, const int2* __restrict__ csr,
                         float* __restrict__ dis, int n) {
    int i = blockIdx.x * blockDim.x + threadIdx.x;
    if (i >= n) return;
    int beg = row_ptr[i], end = row_ptr[i + 1];
    float deg = 1.0f;
    for (int j = beg; j < end; ++j) deg += __int_as_float(csr[j].y);
    dis[i] = rsqrtf(deg);
}

// rewrite csr.y: ew -> dis[src]*ew*dis[dst] (in place, each entry touched once)
__global__ void k_norm(const int* __restrict__ row_ptr, int2* __restrict__ csr,
                       const float* __restrict__ dis, int n) {
    int i = blockIdx.x * blockDim.x + threadIdx.x;
    if (i >= n) return;
    int beg = row_ptr[i], end = row_ptr[i + 1];
    float dd = dis[i];
    for (int j = beg; j < end; ++j) {
        int2 e = csr[j];
        float nm = dis[e.x] * __int_as_float(e.y) * dd;
        csr[j] = make_int2(e.x, __float_as_int(nm));
    }
}

// ---------------- per-layer kernels ----------------

// H = X @ W. 16 threads per row (each owns 4 output cols as float4),
// 16 rows per 256-thread block. Dual float4 accumulators (8 FMA chains).
__global__ void k_gemm(const float4* __restrict__ X4, const float* __restrict__ W,
                       float4* __restrict__ H4, int n) {
    __shared__ float4 w4[FEAT][16];              // w4[k][j4] = W[k][4j4..4j4+3]
    int tid = threadIdx.x;
    for (int t = tid; t < FEAT * 16; t += 256) {
        int k = t >> 4, j4 = t & 15;
        w4[k][j4] = ((const float4*)W)[k * 16 + j4];
    }
    __syncthreads();
    int j4 = tid & 15;                           // col group
    int r  = tid >> 4;                           // row within block
    int i  = blockIdx.x * 16 + r;
    if (i >= n) return;
    const float4* xr = X4 + (size_t)i * 16;
    float4 a0 = make_float4(0.f, 0.f, 0.f, 0.f);
    float4 a1 = make_float4(0.f, 0.f, 0.f, 0.f);
    #pragma unroll
    for (int kk = 0; kk < 16; ++kk) {
        float4 xv = xr[kk];
        int k = kk * 4;
        float4 w0 = w4[k + 0][j4];
        float4 w1 = w4[k + 1][j4];
        float4 w2 = w4[k + 2][j4];
        float4 w3 = w4[k + 3][j4];
        a0 = fma4(xv.x, w0, a0);
        a1 = fma4(xv.y, w1, a1);
        a0 = fma4(xv.z, w2, a0);
        a1 = fma4(xv.w, w3, a1);
    }
    float4 r4;
    r4.x = a0.x + a1.x; r4.y = a0.y + a1.y;
    r4.z = a0.z + a1.z; r4.w = a0.w + a1.w;
    H4[(size_t)i * 16 + j4] = r4;
}

// Conv: 8 lanes/node, each lane owns 8 features (2x float4); 8 nodes/wave.
// 2-edge hand-interleave, 4 independent accumulators -> 4 gathers in
// flight per lane per iteration (32 per wave).
__global__ void k_conv(const float4* __restrict__ H4, const int* __restrict__ row_ptr,
                       const int2* __restrict__ csr, const float* __restrict__ dis,
                       const float4* __restrict__ bias4, float4* __restrict__ OUT4,
                       int n, int do_relu) {
    int t = blockIdx.x * blockDim.x + threadIdx.x;
    int node = t >> 3;
    int sub = t & 7;
    if (node >= n) return;
    int beg = row_ptr[node];
    int end = row_ptr[node + 1];
    float4 a0 = make_float4(0.f, 0.f, 0.f, 0.f);   // even edges, lo half
    float4 a1 = make_float4(0.f, 0.f, 0.f, 0.f);   // even edges, hi half
    float4 c0 = make_float4(0.f, 0.f, 0.f, 0.f);   // odd edges, lo half
    float4 c1 = make_float4(0.f, 0.f, 0.f, 0.f);   // odd edges, hi half
    int j = beg;
    for (; j + 2 <= end; j += 2) {
        int2 e0 = csr[j];
        int2 e1 = csr[j + 1];
        float n0 = __int_as_float(e0.y);
        float n1 = __int_as_float(e1.y);
        float4 h00 = H4[e0.x * 16 + sub];
        float4 h01 = H4[e0.x * 16 + 8 + sub];
        float4 h10 = H4[e1.x * 16 + sub];
        float4 h11 = H4[e1.x * 16 + 8 + sub];
        a0 = fma4(n0, h00, a0);
        a1 = fma4(n0, h01, a1);
        c0 = fma4(n1, h10, c0);
        c1 = fma4(n1, h11, c1);
    }
    if (j < end) {                                 // odd tail
        int2 e0 = csr[j];
        float n0 = __int_as_float(e0.y);
        a0 = fma4(n0, H4[e0.x * 16 + sub], a0);
        a1 = fma4(n0, H4[e0.x * 16 + 8 + sub], a1);
    }
    float di = dis[node];
    float d2 = di * di;
    float4 s0 = H4[node * 16 + sub];
    float4 s1 = H4[node * 16 + 8 + sub];
    float4 bl0 = bias4[sub];
    float4 bl1 = bias4[8 + sub];
    float4 r0, r1;
    r0.x = a0.x + c0.x; r0.y = a0.y + c0.y; r0.z = a0.z + c0.z; r0.w = a0.w + c0.w;
    r1.x = a1.x + c1.x; r1.y = a1.y + c1.y; r1.z = a1.z + c1.z; r1.w = a1.w + c1.w;
    r0 = fma4(d2, s0, r0);
    r1 = fma4(d2, s1, r1);
    r0.x += bl0.x; r0.y += bl0.y; r0.z += bl0.z; r0.w += bl0.w;
    r1.x += bl1.x; r1.y += bl1.y; r1.z += bl1.z; r1.w += bl1.w;
    if (do_relu) {
        r0.x = fmaxf(r0.x, 0.f); r0.y = fmaxf(r0.y, 0.f);
        r0.z = fmaxf(r0.z, 0.f); r0.w = fmaxf(r0.w, 0.f);
        r1.x = fmaxf(r1.x, 0.f); r1.y = fmaxf(r1.y, 0.f);
        r1.z = fmaxf(r1.z, 0.f); r1.w = fmaxf(r1.w, 0.f);
    }
    OUT4[node * 16 + sub] = r0;
    OUT4[node * 16 + 8 + sub] = r1;
}

// ---------------- pooling + head ----------------

// Segmented sum over sorted batch: one wave per POOL_SPAN nodes, lane = feature.
__global__ void k_pool(const float* __restrict__ H, const int* __restrict__ batch,
                       float* __restrict__ sums, int n) {
    int wid = (blockIdx.x * blockDim.x + threadIdx.x) >> 6;
    int lane = threadIdx.x & 63;
    int beg = wid * POOL_SPAN;
    if (beg >= n) return;
    int end = min(beg + POOL_SPAN, n);
    float acc = 0.f;
    int cur = batch[beg];
    for (int i = beg; i < end; ++i) {
        int g = batch[i];                        // wave-uniform broadcast
        if (g != cur) {                          // wave-uniform branch
            atomicAdd(&sums[cur * FEAT + lane], acc);
            acc = 0.f;
            cur = g;
        }
        acc += H[(size_t)i * FEAT + lane];       // coalesced 256B/wave
    }
    atomicAdd(&sums[cur * FEAT + lane], acc);
}

__device__ __forceinline__ int lb(const int* __restrict__ a, int n, int v) {
    int lo = 0, hi = n;
    while (lo < hi) { int m = (lo + hi) >> 1; if (a[m] < v) lo = m + 1; else hi = m; }
    return lo;
}

// mean + linear head fused: out[g][c] = bl[c] + (sums[g]/cnt_g) . Wl[:,c]
__global__ void k_head(const float* __restrict__ sums, const int* __restrict__ batch,
                       int n, const float* __restrict__ Wl, const float* __restrict__ bl,
                       float* __restrict__ out, int C) {
    int t = threadIdx.x;
    if (t >= NGRAPH * C) return;
    int g = t / C, c = t % C;
    int start = lb(batch, n, g);
    int end = lb(batch, n, g + 1);
    float inv = 1.0f / fmaxf((float)(end - start), 1.0f);
    float acc = bl[c];
    #pragma unroll
    for (int f = 0; f < FEAT; ++f)
        acc = fmaf(sums[g * FEAT + f] * inv, Wl[f * C + c], acc);
    out[g * C + c] = acc;
}

// ---------------- launch ----------------

extern "C" void kernel_launch(void* const* d_in, const int* in_sizes, int n_in,
                              void* d_out, int out_size, void* d_ws, size_t ws_size,
                              hipStream_t stream) {
    const float* x     = (const float*)d_in[0];
    const int*   ei    = (const int*)d_in[1];
    const float* ew    = (const float*)d_in[2];
    const int*   batch = (const int*)d_in[3];
    const float* W1 = (const float*)d_in[4];
    const float* b1 = (const float*)d_in[5];
    const float* W2 = (const float*)d_in[6];
    const float* b2 = (const float*)d_in[7];
    const float* W3 = (const float*)d_in[8];
    const float* b3 = (const float*)d_in[9];
    const float* Wl = (const float*)d_in[10];
    const float* bl = (const float*)d_in[11];
    float* out = (float*)d_out;

    const int N = in_sizes[3];          // batch has N elements
    const int E = in_sizes[2];          // edge_attr has E elements
    const int C = in_sizes[11];         // bl has C elements

    const int* src = ei;
    const int* dst = ei + E;

    // workspace carve-up (256B-aligned); dry-run to verify ws_size first
    size_t need = 0;
    auto sz = [&](size_t bytes) { need += (bytes + 255) & ~(size_t)255; };
    sz((size_t)N * 4); sz((size_t)N * 4); sz((size_t)(N + 1) * 4);
    sz((size_t)E * 4); sz((size_t)SCAN_BLK * 4);
    sz((size_t)E * 8);
    sz((size_t)N * FEAT * 4); sz((size_t)N * FEAT * 4);
    sz((size_t)NGRAPH * FEAT * 4);
    if (need > ws_size) return;   // fail readable (zero output), not fatal

    char* p = (char*)d_ws;
    auto carve = [&](size_t bytes) {
        char* r = p;
        p += (bytes + 255) & ~(size_t)255;
        return r;
    };
    float* dis      = (float*)carve((size_t)N * 4);
    int*   cnt      = (int*)  carve((size_t)N * 4);
    int*   row_ptr  = (int*)  carve((size_t)(N + 1) * 4);
    int*   rank     = (int*)  carve((size_t)E * 4);
    int*   part     = (int*)  carve((size_t)SCAN_BLK * 4);
    int2*  csr      = (int2*) carve((size_t)E * 8);
    float* bufA     = (float*)carve((size_t)N * FEAT * 4);
    float* bufB     = (float*)carve((size_t)N * FEAT * 4);
    float* sums     = (float*)carve((size_t)NGRAPH * FEAT * 4);

    const int blkN  = (N + 255) / 256;
    const int blkE  = (E + 255) / 256;
    const int nScan = (N + SCAN_BLK - 1) / SCAN_BLK;
    const int blkC  = (N * 8 + 255) / 256;       // conv: 8 lanes/node
    const int blkG  = (N + 15) / 16;             // gemm: 16 rows/block
    const int blkP  = (N + 4 * POOL_SPAN - 1) / (4 * POOL_SPAN);  // 4 waves/block

    // zero cnt + sums (capture-safe async memsets; harness uses these itself)
    hipMemsetAsync(cnt, 0, (size_t)N * 4, stream);
    hipMemsetAsync(sums, 0, (size_t)NGRAPH * FEAT * 4, stream);

    // structure preprocessing (layer-invariant)
    k_cnt<<<blkE, 256, 0, stream>>>(dst, cnt, rank, E);
    k_scan_block<<<nScan, SCAN_BLK, 0, stream>>>(cnt, N, row_ptr, part);
    k_scan_top<<<1, SCAN_BLK, 0, stream>>>(part, nScan);
    k_scan_add<<<blkN, 256, 0, stream>>>(row_ptr, part, N, E);
    k_fill<<<blkE, 256, 0, stream>>>(src, dst, ew, rank, row_ptr, csr, E);
    k_degdis<<<blkN, 256, 0, stream>>>(row_ptr, csr, dis, N);
    k_norm<<<blkN, 256, 0, stream>>>(row_ptr, csr, dis, N);

    // layer 1
    k_gemm<<<blkG, 256, 0, stream>>>((const float4*)x, W1, (float4*)bufA, N);
    k_conv<<<blkC, 256, 0, stream>>>((const float4*)bufA, row_ptr, csr, dis,
                                     (const float4*)b1, (float4*)bufB, N, 1);
    // layer 2
    k_gemm<<<blkG, 256, 0, stream>>>((const float4*)bufB, W2, (float4*)bufA, N);
    k_conv<<<blkC, 256, 0, stream>>>((const float4*)bufA, row_ptr, csr, dis,
                                     (const float4*)b2, (float4*)bufB, N, 1);
    // layer 3
    k_gemm<<<blkG, 256, 0, stream>>>((const float4*)bufB, W3, (float4*)bufA, N);
    k_conv<<<blkC, 256, 0, stream>>>((const float4*)bufA, row_ptr, csr, dis,
                                     (const float4*)b3, (float4*)bufB, N, 0);

    // pool + head
    k_pool<<<blkP, 256, 0, stream>>>(bufB, batch, sums, N);
    k_head<<<1, 64, 0, stream>>>(sums, batch, N, Wl, bl, out, C);
}

// Round 16
// 317.331 us; speedup vs baseline: 1.0299x; 1.0299x over previous
//
#include <hip/hip_runtime.h>

// GCN: 3x GCNConv(64->64) + mean-pool(32 graphs) + linear(64->2), fp32.
// Preproc: histogram WITH RANK CAPTURE -> scan -> CSR fill (no atomics).
// Layers: gemm1 standalone; conv1+gemm2 and conv2+gemm3 FUSED via LDS
// (saves 2 launches + 2x 25.6MB H round-trips); conv3 standalone; pool; head.

#define FEAT 64
#define NGRAPH 32
#define SCAN_BLK 512
#define POOL_SPAN 64

__device__ __forceinline__ float4 fma4(float s, float4 v, float4 a) {
    a.x = fmaf(s, v.x, a.x); a.y = fmaf(s, v.y, a.y);
    a.z = fmaf(s, v.z, a.z); a.w = fmaf(s, v.w, a.w);
    return a;
}

// ---------------- preprocessing ----------------

__global__ void k_cnt(const int* __restrict__ dst, int* __restrict__ cnt,
                      int* __restrict__ rank, int e) {
    int i = blockIdx.x * blockDim.x + threadIdx.x;
    int stride = gridDim.x * blockDim.x;
    for (; i < e; i += stride) rank[i] = atomicAdd(&cnt[dst[i]], 1);
}

__global__ void k_scan_block(const int* __restrict__ cnt, int n,
                             int* __restrict__ row_ptr, int* __restrict__ part) {
    __shared__ int s[SCAN_BLK];
    int tid = threadIdx.x;
    int i = blockIdx.x * SCAN_BLK + tid;
    int v = (i < n) ? cnt[i] : 0;
    s[tid] = v;
    __syncthreads();
    for (int o = 1; o < SCAN_BLK; o <<= 1) {
        int t = (tid >= o) ? s[tid - o] : 0;
        __syncthreads();
        s[tid] += t;
        __syncthreads();
    }
    if (i < n) row_ptr[i] = s[tid] - v;
    if (tid == SCAN_BLK - 1) part[blockIdx.x] = s[tid];
}

__global__ void k_scan_top(int* __restrict__ part, int nb) {
    __shared__ int s[SCAN_BLK];
    int tid = threadIdx.x;
    int v = (tid < nb) ? part[tid] : 0;
    s[tid] = v;
    __syncthreads();
    for (int o = 1; o < SCAN_BLK; o <<= 1) {
        int t = (tid >= o) ? s[tid - o] : 0;
        __syncthreads();
        s[tid] += t;
        __syncthreads();
    }
    if (tid < nb) part[tid] = s[tid] - v;
}

__global__ void k_scan_add(int* __restrict__ row_ptr, const int* __restrict__ part,
                           int n, int e) {
    int i = blockIdx.x * blockDim.x + threadIdx.x;
    if (i < n) row_ptr[i] += part[i >> 9];
    if (i == 0) row_ptr[n] = e;
}

__global__ void k_fill(const int* __restrict__ src, const int* __restrict__ dst,
                       const float* __restrict__ ew, const int* __restrict__ rank,
                       const int* __restrict__ row_ptr, int2* __restrict__ csr, int e) {
    int i = blockIdx.x * blockDim.x + threadIdx.x;
    int stride = gridDim.x * blockDim.x;
    for (; i < e; i += stride) {
        int pos = row_ptr[dst[i]] + rank[i];
        csr[pos] = make_int2(src[i], __float_as_int(ew[i]));
    }
}

__global__ void k_degdis(const int* __restrict__ row_ptr, const int2* __restrict__ csr,
                         float* __restrict__ dis, int n) {
    int i = blockIdx.x * blockDim.x + threadIdx.x;
    if (i >= n) return;
    int beg = row_ptr[i], end = row_ptr[i + 1];
    float deg = 1.0f;
    for (int j = beg; j < end; ++j) deg += __int_as_float(csr[j].y);
    dis[i] = rsqrtf(deg);
}

__global__ void k_norm(const int* __restrict__ row_ptr, int2* __restrict__ csr,
                       const float* __restrict__ dis, int n) {
    int i = blockIdx.x * blockDim.x + threadIdx.x;
    if (i >= n) return;
    int beg = row_ptr[i], end = row_ptr[i + 1];
    float dd = dis[i];
    for (int j = beg; j < end; ++j) {
        int2 e = csr[j];
        float nm = dis[e.x] * __int_as_float(e.y) * dd;
        csr[j] = make_int2(e.x, __float_as_int(nm));
    }
}

// ---------------- per-layer kernels ----------------

// Standalone GEMM (layer 1): 16 threads/row, 16 rows/block, dual accumulators.
__global__ void k_gemm(const float4* __restrict__ X4, const float* __restrict__ W,
                       float4* __restrict__ H4, int n) {
    __shared__ float4 w4[FEAT][16];
    int tid = threadIdx.x;
    for (int t = tid; t < FEAT * 16; t += 256) {
        int k = t >> 4, j4 = t & 15;
        w4[k][j4] = ((const float4*)W)[k * 16 + j4];
    }
    __syncthreads();
    int j4 = tid & 15;
    int r  = tid >> 4;
    int i  = blockIdx.x * 16 + r;
    if (i >= n) return;
    const float4* xr = X4 + (size_t)i * 16;
    float4 a0 = make_float4(0.f, 0.f, 0.f, 0.f);
    float4 a1 = make_float4(0.f, 0.f, 0.f, 0.f);
    #pragma unroll
    for (int kk = 0; kk < 16; ++kk) {
        float4 xv = xr[kk];
        int k = kk * 4;
        a0 = fma4(xv.x, w4[k + 0][j4], a0);
        a1 = fma4(xv.y, w4[k + 1][j4], a1);
        a0 = fma4(xv.z, w4[k + 2][j4], a0);
        a1 = fma4(xv.w, w4[k + 3][j4], a1);
    }
    float4 r4;
    r4.x = a0.x + a1.x; r4.y = a0.y + a1.y;
    r4.z = a0.z + a1.z; r4.w = a0.w + a1.w;
    H4[(size_t)i * 16 + j4] = r4;
}

// Standalone conv (layer 3, no relu): 8 lanes/node, 2-edge interleave.
__global__ void k_conv(const float4* __restrict__ H4, const int* __restrict__ row_ptr,
                       const int2* __restrict__ csr, const float* __restrict__ dis,
                       const float4* __restrict__ bias4, float4* __restrict__ OUT4,
                       int n, int do_relu) {
    int t = blockIdx.x * blockDim.x + threadIdx.x;
    int node = t >> 3;
    int sub = t & 7;
    if (node >= n) return;
    int beg = row_ptr[node];
    int end = row_ptr[node + 1];
    float4 a0 = make_float4(0.f, 0.f, 0.f, 0.f);
    float4 a1 = make_float4(0.f, 0.f, 0.f, 0.f);
    float4 c0 = make_float4(0.f, 0.f, 0.f, 0.f);
    float4 c1 = make_float4(0.f, 0.f, 0.f, 0.f);
    int j = beg;
    for (; j + 2 <= end; j += 2) {
        int2 e0 = csr[j];
        int2 e1 = csr[j + 1];
        float n0 = __int_as_float(e0.y);
        float n1 = __int_as_float(e1.y);
        a0 = fma4(n0, H4[e0.x * 16 + sub], a0);
        a1 = fma4(n0, H4[e0.x * 16 + 8 + sub], a1);
        c0 = fma4(n1, H4[e1.x * 16 + sub], c0);
        c1 = fma4(n1, H4[e1.x * 16 + 8 + sub], c1);
    }
    if (j < end) {
        int2 e0 = csr[j];
        float n0 = __int_as_float(e0.y);
        a0 = fma4(n0, H4[e0.x * 16 + sub], a0);
        a1 = fma4(n0, H4[e0.x * 16 + 8 + sub], a1);
    }
    float di = dis[node];
    float d2 = di * di;
    float4 r0, r1;
    r0.x = a0.x + c0.x; r0.y = a0.y + c0.y; r0.z = a0.z + c0.z; r0.w = a0.w + c0.w;
    r1.x = a1.x + c1.x; r1.y = a1.y + c1.y; r1.z = a1.z + c1.z; r1.w = a1.w + c1.w;
    r0 = fma4(d2, H4[node * 16 + sub], r0);
    r1 = fma4(d2, H4[node * 16 + 8 + sub], r1);
    float4 bl0 = bias4[sub];
    float4 bl1 = bias4[8 + sub];
    r0.x += bl0.x; r0.y += bl0.y; r0.z += bl0.z; r0.w += bl0.w;
    r1.x += bl1.x; r1.y += bl1.y; r1.z += bl1.z; r1.w += bl1.w;
    if (do_relu) {
        r0.x = fmaxf(r0.x, 0.f); r0.y = fmaxf(r0.y, 0.f);
        r0.z = fmaxf(r0.z, 0.f); r0.w = fmaxf(r0.w, 0.f);
        r1.x = fmaxf(r1.x, 0.f); r1.y = fmaxf(r1.y, 0.f);
        r1.z = fmaxf(r1.z, 0.f); r1.w = fmaxf(r1.w, 0.f);
    }
    OUT4[node * 16 + sub] = r0;
    OUT4[node * 16 + 8 + sub] = r1;
}

// FUSED conv+next-gemm: block = 32 nodes. Phase 1: aggregate+bias+relu ->
// LDS rows (padded stride 17 to avoid cross-row bank conflicts).
// Phase 2: rows @ Wn from LDS (two 16-row passes of the proven gemm pattern).
__global__ void k_convgemm(const float4* __restrict__ H4, const int* __restrict__ row_ptr,
                           const int2* __restrict__ csr, const float* __restrict__ dis,
                           const float4* __restrict__ bias4, const float* __restrict__ Wn,
                           float4* __restrict__ OUT4, int n) {
    __shared__ float4 w4[FEAT][16];              // 16 KB: next-layer W
    __shared__ float4 hrow[32][17];              // 8.7 KB: padded activation rows
    int tid = threadIdx.x;
    for (int t = tid; t < FEAT * 16; t += 256) {
        int k = t >> 4, j4 = t & 15;
        w4[k][j4] = ((const float4*)Wn)[k * 16 + j4];
    }

    // ---- phase 1: aggregation (8 lanes/node, 32 nodes/block) ----
    int lr   = tid >> 3;                         // local row 0..31
    int sub  = tid & 7;
    int node = blockIdx.x * 32 + lr;
    bool valid = node < n;
    if (valid) {
        int beg = row_ptr[node];
        int end = row_ptr[node + 1];
        float4 a0 = make_float4(0.f, 0.f, 0.f, 0.f);
        float4 a1 = make_float4(0.f, 0.f, 0.f, 0.f);
        float4 c0 = make_float4(0.f, 0.f, 0.f, 0.f);
        float4 c1 = make_float4(0.f, 0.f, 0.f, 0.f);
        int j = beg;
        for (; j + 2 <= end; j += 2) {
            int2 e0 = csr[j];
            int2 e1 = csr[j + 1];
            float n0 = __int_as_float(e0.y);
            float n1 = __int_as_float(e1.y);
            a0 = fma4(n0, H4[e0.x * 16 + sub], a0);
            a1 = fma4(n0, H4[e0.x * 16 + 8 + sub], a1);
            c0 = fma4(n1, H4[e1.x * 16 + sub], c0);
            c1 = fma4(n1, H4[e1.x * 16 + 8 + sub], c1);
        }
        if (j < end) {
            int2 e0 = csr[j];
            float n0 = __int_as_float(e0.y);
            a0 = fma4(n0, H4[e0.x * 16 + sub], a0);
            a1 = fma4(n0, H4[e0.x * 16 + 8 + sub], a1);
        }
        float di = dis[node];
        float d2 = di * di;
        float4 r0, r1;
        r0.x = a0.x + c0.x; r0.y = a0.y + c0.y; r0.z = a0.z + c0.z; r0.w = a0.w + c0.w;
        r1.x = a1.x + c1.x; r1.y = a1.y + c1.y; r1.z = a1.z + c1.z; r1.w = a1.w + c1.w;
        r0 = fma4(d2, H4[node * 16 + sub], r0);
        r1 = fma4(d2, H4[node * 16 + 8 + sub], r1);
        float4 bl0 = bias4[sub];
        float4 bl1 = bias4[8 + sub];
        // bias + relu (fused layers are 1 and 2 -> always relu)
        r0.x = fmaxf(r0.x + bl0.x, 0.f); r0.y = fmaxf(r0.y + bl0.y, 0.f);
        r0.z = fmaxf(r0.z + bl0.z, 0.f); r0.w = fmaxf(r0.w + bl0.w, 0.f);
        r1.x = fmaxf(r1.x + bl1.x, 0.f); r1.y = fmaxf(r1.y + bl1.y, 0.f);
        r1.z = fmaxf(r1.z + bl1.z, 0.f); r1.w = fmaxf(r1.w + bl1.w, 0.f);
        hrow[lr][sub] = r0;
        hrow[lr][8 + sub] = r1;
    }
    __syncthreads();

    // ---- phase 2: rows @ Wn (two 16-row passes, 16 threads/row) ----
    int j4 = tid & 15;
    int rr = tid >> 4;                           // 0..15
    #pragma unroll
    for (int half = 0; half < 2; ++half) {
        int lrow = rr + half * 16;
        int grow = blockIdx.x * 32 + lrow;
        if (grow < n) {
            const float4* xr = hrow[lrow];
            float4 a0 = make_float4(0.f, 0.f, 0.f, 0.f);
            float4 a1 = make_float4(0.f, 0.f, 0.f, 0.f);
            #pragma unroll
            for (int kk = 0; kk < 16; ++kk) {
                float4 xv = xr[kk];
                int k = kk * 4;
                a0 = fma4(xv.x, w4[k + 0][j4], a0);
                a1 = fma4(xv.y, w4[k + 1][j4], a1);
                a0 = fma4(xv.z, w4[k + 2][j4], a0);
                a1 = fma4(xv.w, w4[k + 3][j4], a1);
            }
            float4 r4;
            r4.x = a0.x + a1.x; r4.y = a0.y + a1.y;
            r4.z = a0.z + a1.z; r4.w = a0.w + a1.w;
            OUT4[(size_t)grow * 16 + j4] = r4;
        }
    }
}

// ---------------- pooling + head ----------------

__global__ void k_pool(const float* __restrict__ H, const int* __restrict__ batch,
                       float* __restrict__ sums, int n) {
    int wid = (blockIdx.x * blockDim.x + threadIdx.x) >> 6;
    int lane = threadIdx.x & 63;
    int beg = wid * POOL_SPAN;
    if (beg >= n) return;
    int end = min(beg + POOL_SPAN, n);
    float acc = 0.f;
    int cur = batch[beg];
    for (int i = beg; i < end; ++i) {
        int g = batch[i];
        if (g != cur) {
            atomicAdd(&sums[cur * FEAT + lane], acc);
            acc = 0.f;
            cur = g;
        }
        acc += H[(size_t)i * FEAT + lane];
    }
    atomicAdd(&sums[cur * FEAT + lane], acc);
}

__device__ __forceinline__ int lb(const int* __restrict__ a, int n, int v) {
    int lo = 0, hi = n;
    while (lo < hi) { int m = (lo + hi) >> 1; if (a[m] < v) lo = m + 1; else hi = m; }
    return lo;
}

__global__ void k_head(const float* __restrict__ sums, const int* __restrict__ batch,
                       int n, const float* __restrict__ Wl, const float* __restrict__ bl,
                       float* __restrict__ out, int C) {
    int t = threadIdx.x;
    if (t >= NGRAPH * C) return;
    int g = t / C, c = t % C;
    int start = lb(batch, n, g);
    int end = lb(batch, n, g + 1);
    float inv = 1.0f / fmaxf((float)(end - start), 1.0f);
    float acc = bl[c];
    #pragma unroll
    for (int f = 0; f < FEAT; ++f)
        acc = fmaf(sums[g * FEAT + f] * inv, Wl[f * C + c], acc);
    out[g * C + c] = acc;
}

// ---------------- launch ----------------

extern "C" void kernel_launch(void* const* d_in, const int* in_sizes, int n_in,
                              void* d_out, int out_size, void* d_ws, size_t ws_size,
                              hipStream_t stream) {
    const float* x     = (const float*)d_in[0];
    const int*   ei    = (const int*)d_in[1];
    const float* ew    = (const float*)d_in[2];
    const int*   batch = (const int*)d_in[3];
    const float* W1 = (const float*)d_in[4];
    const float* b1 = (const float*)d_in[5];
    const float* W2 = (const float*)d_in[6];
    const float* b2 = (const float*)d_in[7];
    const float* W3 = (const float*)d_in[8];
    const float* b3 = (const float*)d_in[9];
    const float* Wl = (const float*)d_in[10];
    const float* bl = (const float*)d_in[11];
    float* out = (float*)d_out;

    const int N = in_sizes[3];
    const int E = in_sizes[2];
    const int C = in_sizes[11];

    const int* src = ei;
    const int* dst = ei + E;

    size_t need = 0;
    auto sz = [&](size_t bytes) { need += (bytes + 255) & ~(size_t)255; };
    sz((size_t)N * 4); sz((size_t)N * 4); sz((size_t)(N + 1) * 4);
    sz((size_t)E * 4); sz((size_t)SCAN_BLK * 4);
    sz((size_t)E * 8);
    sz((size_t)N * FEAT * 4); sz((size_t)N * FEAT * 4);
    sz((size_t)NGRAPH * FEAT * 4);
    if (need > ws_size) return;

    char* p = (char*)d_ws;
    auto carve = [&](size_t bytes) {
        char* r = p;
        p += (bytes + 255) & ~(size_t)255;
        return r;
    };
    float* dis      = (float*)carve((size_t)N * 4);
    int*   cnt      = (int*)  carve((size_t)N * 4);
    int*   row_ptr  = (int*)  carve((size_t)(N + 1) * 4);
    int*   rank     = (int*)  carve((size_t)E * 4);
    int*   part     = (int*)  carve((size_t)SCAN_BLK * 4);
    int2*  csr      = (int2*) carve((size_t)E * 8);
    float* bufA     = (float*)carve((size_t)N * FEAT * 4);
    float* bufB     = (float*)carve((size_t)N * FEAT * 4);
    float* sums     = (float*)carve((size_t)NGRAPH * FEAT * 4);

    const int blkN  = (N + 255) / 256;
    const int blkE  = (E + 255) / 256;
    const int nScan = (N + SCAN_BLK - 1) / SCAN_BLK;
    const int blkC  = (N * 8 + 255) / 256;       // conv: 8 lanes/node
    const int blkF  = (N + 31) / 32;             // fused: 32 nodes/block
    const int blkG  = (N + 15) / 16;             // gemm: 16 rows/block
    const int blkP  = (N + 4 * POOL_SPAN - 1) / (4 * POOL_SPAN);

    hipMemsetAsync(cnt, 0, (size_t)N * 4, stream);
    hipMemsetAsync(sums, 0, (size_t)NGRAPH * FEAT * 4, stream);

    // structure preprocessing (layer-invariant)
    k_cnt<<<blkE, 256, 0, stream>>>(dst, cnt, rank, E);
    k_scan_block<<<nScan, SCAN_BLK, 0, stream>>>(cnt, N, row_ptr, part);
    k_scan_top<<<1, SCAN_BLK, 0, stream>>>(part, nScan);
    k_scan_add<<<blkN, 256, 0, stream>>>(row_ptr, part, N, E);
    k_fill<<<blkE, 256, 0, stream>>>(src, dst, ew, rank, row_ptr, csr, E);
    k_degdis<<<blkN, 256, 0, stream>>>(row_ptr, csr, dis, N);
    k_norm<<<blkN, 256, 0, stream>>>(row_ptr, csr, dis, N);

    // layer 1 GEMM
    k_gemm<<<blkG, 256, 0, stream>>>((const float4*)x, W1, (float4*)bufA, N);
    // conv1 + gemm2 fused
    k_convgemm<<<blkF, 256, 0, stream>>>((const float4*)bufA, row_ptr, csr, dis,
                                         (const float4*)b1, W2, (float4*)bufB, N);
    // conv2 + gemm3 fused
    k_convgemm<<<blkF, 256, 0, stream>>>((const float4*)bufB, row_ptr, csr, dis,
                                         (const float4*)b2, W3, (float4*)bufA, N);
    // conv3 (no relu)
    k_conv<<<blkC, 256, 0, stream>>>((const float4*)bufA, row_ptr, csr, dis,
                                     (const float4*)b3, (float4*)bufB, N, 0);

    // pool + head
    k_pool<<<blkP, 256, 0, stream>>>(bufB, batch, sums, N);
    k_head<<<1, 64, 0, stream>>>(sums, batch, N, Wl, bl, out, C);
}